// Round 12
// baseline (99.145 us; speedup 1.0000x reference)
//
#include <hip/hip_runtime.h>
#include <math.h>

// Problem dims (fixed by setup_inputs): inp [1,2,48,160,160] f32, target [1,48,160,160] i32
#define D_ 48
#define H_ 160
#define W_ 160
#define HW_ 25600
#define N_ 1228800
#define NBLK 4800          // N_/256
#define HBLK 600           // 8 elems/thread passes
#define K1_ 1216512u       // 1-based rank of sorted index floor(0.99*(N-1)); frac==0 in f32 (R1: absmax 0.0)

static_assert(N_ == D_ * HW_, "dims");
static_assert(N_ == NBLK * 256, "grid");
static_assert(N_ == HBLK * 256 * 8, "hist grid");

// ---- workspace layout (bytes) ----
#define OFF_KL  0u
#define OFF_FA  (N_ * 4u)
#define OFF_FB  (2u * N_ * 4u)
#define OFF_G1  (3u * N_ * 4u)            // 4096 u32
#define OFF_G2  (OFF_G1 + 4096u * 4u)     // 4096 u32
#define OFF_G3  (OFF_G2 + 4096u * 4u)     // 256 u32
#define OFF_SC  (OFF_G3 + 256u * 4u)      // 16 u32 scalars
#define OFF_PS  (OFF_SC + 64u)
#define OFF_PC  (OFF_PS + NBLK * 4u)
#define ZERO_WORDS (4096u + 4096u + 256u + 16u)   // g1,g2,g3,sc contiguous = 8464 u32
// scalars: sc[0]=b1 sc[1]=rank1 sc[2]=b2 sc[3]=rank2 sc[4]=b3 sc[5]=rank3 sc[6]=thr bits

__device__ __forceinline__ unsigned fkey(float v) {
  unsigned u = __float_as_uint(v);
  return (u & 0x80000000u) ? ~u : (u | 0x80000000u);  // monotone map: float asc -> uint asc
}

// ---------------- zero g1+g2+g3+sc (replaces the 40us hipMemsetAsync of R2) ----------------
__global__ __launch_bounds__(256) void k_zero(unsigned* __restrict__ g1) {
  const unsigned i = blockIdx.x * 256u + threadIdx.x;
  if (i < ZERO_WORDS) g1[i] = 0u;
}

// ---------------- kl_vals + initial dist field + level-1 (hi-12) histogram ----------------
__global__ __launch_bounds__(256) void k_prep(const float* __restrict__ inp,
                                              const int* __restrict__ tgt,
                                              float* __restrict__ kl,
                                              float* __restrict__ f0,
                                              unsigned* __restrict__ ghist) {
  __shared__ unsigned h[4096];
  const int tid = threadIdx.x;
  for (int i = tid; i < 4096; i += 256) h[i] = 0;
  __syncthreads();
  const int base = blockIdx.x * 2048;
  for (int e = 0; e < 8; e++) {
    const int idx = base + e * 256 + tid;
    const int ww = idx % W_;
    const int hh = (idx / W_) % H_;
    const int dd = idx / HW_;
    const float p0 = inp[idx];
    const float p1 = inp[N_ + idx];

    float klh = -1.0f, klv = -1.0f, kld = -1.0f;
    if (ww < W_ - 1) {
      const float t0 = inp[idx + 1], t1 = inp[N_ + idx + 1];
      const float a0 = (t0 > 0.f) ? t0 * logf(t0) : 0.f;
      const float a1 = (t1 > 0.f) ? t1 * logf(t1) : 0.f;
      klh = 0.5f * ((a0 - t0 * p0) + (a1 - t1 * p1));
    }
    if (hh < H_ - 1) {
      const float t0 = inp[idx + W_], t1 = inp[N_ + idx + W_];
      const float a0 = (t0 > 0.f) ? t0 * logf(t0) : 0.f;
      const float a1 = (t1 > 0.f) ? t1 * logf(t1) : 0.f;
      klv = 0.5f * ((a0 - t0 * p0) + (a1 - t1 * p1));
    }
    if (dd < D_ - 1) {
      const float t0 = inp[idx + HW_], t1 = inp[N_ + idx + HW_];
      const float a0 = (t0 > 0.f) ? t0 * logf(t0) : 0.f;
      const float a1 = (t1 > 0.f) ? t1 * logf(t1) : 0.f;
      kld = 0.5f * ((a0 - t0 * p0) + (a1 - t1 * p1));
    }
    const float kmax = fmaxf(fmaxf(klh, klv), kld);
    kl[idx] = kmax;
    atomicAdd(&h[fkey(kmax) >> 20], 1u);

    const int tv = tgt[idx];
    const int t1 = (ww < W_ - 1) ? tgt[idx + 1] : 0;
    const int t2 = (hh < H_ - 1) ? tgt[idx + W_] : 0;
    const int t3 = (dd < D_ - 1) ? tgt[idx + HW_] : 0;
    f0[idx] = (3 * tv != t1 + t2 + t3) ? 0.f : 1e10f;
  }
  __syncthreads();
  for (int i = tid; i < 4096; i += 256) {
    const unsigned c = h[i];
    if (c) atomicAdd(&ghist[i], c);
  }
}

// ---------------- EDT pass along one axis, early-exit outward scan (bit-exact) ----------------
// Since f>=0, RN(f[j]+r^2) >= r^2, so once r^2 >= m no candidate can lower the min; min over
// a set is order-independent -> identical bits vs brute force.
template <int STRIDE, int LEN, int AXIS, bool DOSQRT>
__global__ __launch_bounds__(256) void k_dt(const float* __restrict__ fin,
                                            float* __restrict__ fout) {
  const int idx = blockIdx.x * 256 + threadIdx.x;
  const int pos = (AXIS == 0) ? (idx / HW_) : ((AXIS == 1) ? ((idx / W_) % H_) : (idx % W_));
  float m = fin[idx];
  for (int r = 1; r < LEN; r++) {
    const float r2 = (float)(r * r);
    if (r2 >= m) break;
    const int jm = pos - r, jp = pos + r;
    const bool okm = (jm >= 0), okp = (jp < LEN);
    if (!okm && !okp) break;
    if (okm) m = fminf(m, fin[idx - r * STRIDE] + r2);
    if (okp) m = fminf(m, fin[idx + r * STRIDE] + r2);
  }
  fout[idx] = DOSQRT ? sqrtf(m) : m;
}

// ---------------- generic rank-select over a histogram (nb = 256*chunk buckets) ----------------
__global__ __launch_bounds__(256) void k_sel(const unsigned* __restrict__ hist, int nb,
                                             const unsigned* __restrict__ Kp, unsigned Kimm,
                                             unsigned* __restrict__ outB,
                                             unsigned* __restrict__ outR) {
  __shared__ unsigned ssum[256];
  __shared__ unsigned spre[256];
  const int t = threadIdx.x;
  const unsigned K = Kp ? *Kp : Kimm;
  const int chunk = nb >> 8;
  unsigned s = 0;
  for (int i = 0; i < chunk; i++) s += hist[t * chunk + i];
  ssum[t] = s;
  __syncthreads();
  if (t == 0) {
    unsigned c = 0;
    for (int i = 0; i < 256; i++) { spre[i] = c; c += ssum[i]; }
  }
  __syncthreads();
  const unsigned before = spre[t];
  if (before < K && K <= before + ssum[t]) {
    unsigned cum = before;
    for (int i = 0; i < chunk; i++) {
      const unsigned c = hist[t * chunk + i];
      if (cum < K && K <= cum + c) { *outB = (unsigned)(t * chunk + i); *outR = K - cum; break; }
      cum += c;
    }
  }
}

// ---------------- level-2 histogram: mid-12 bits within selected hi-12 bucket ----------------
__global__ __launch_bounds__(256) void k_hist2(const float* __restrict__ kl,
                                               const unsigned* __restrict__ sc,
                                               unsigned* __restrict__ ghist) {
  __shared__ unsigned h[4096];
  const int tid = threadIdx.x;
  for (int i = tid; i < 4096; i += 256) h[i] = 0;
  __syncthreads();
  const unsigned b1 = sc[0];
  const int base = blockIdx.x * 2048;
  for (int e = 0; e < 8; e++) {
    const int idx = base + e * 256 + tid;
    const unsigned key = fkey(kl[idx]);
    if ((key >> 20) == b1) atomicAdd(&h[(key >> 8) & 0xFFFu], 1u);
  }
  __syncthreads();
  for (int i = tid; i < 4096; i += 256) {
    const unsigned c = h[i];
    if (c) atomicAdd(&ghist[i], c);
  }
}

// ---------------- level-3 histogram: low-8 bits within selected hi-24 prefix ----------------
__global__ __launch_bounds__(256) void k_hist3(const float* __restrict__ kl,
                                               const unsigned* __restrict__ sc,
                                               unsigned* __restrict__ ghist) {
  __shared__ unsigned h[256];
  const int tid = threadIdx.x;
  h[tid] = 0;
  __syncthreads();
  const unsigned hi24 = (sc[0] << 12) | sc[2];
  const int base = blockIdx.x * 2048;
  for (int e = 0; e < 8; e++) {
    const int idx = base + e * 256 + tid;
    const unsigned key = fkey(kl[idx]);
    if ((key >> 8) == hi24) atomicAdd(&h[key & 0xFFu], 1u);
  }
  __syncthreads();
  const unsigned c = h[tid];
  if (c) atomicAdd(&ghist[tid], c);
}

// thr = order statistic at rank K1 (frac term is exactly 0, verified bit-exact since R1)
__global__ void k_thr(unsigned* sc) {
  const unsigned key = (sc[0] << 20) | (sc[2] << 8) | sc[4];
  sc[6] = (key & 0x80000000u) ? (key & 0x7FFFFFFFu) : ~key;  // inverse of fkey
}

// ---------------- masked loss at each voxel + block partials ----------------
__global__ __launch_bounds__(256) void k_loss(const float* __restrict__ inp,
                                              const float* __restrict__ kl,
                                              const float* __restrict__ gdist,
                                              const unsigned* __restrict__ sc,
                                              float* __restrict__ psum,
                                              unsigned* __restrict__ pcnt) {
  const int tid = threadIdx.x;
  const int idx = blockIdx.x * 256 + tid;
  const float thr = __uint_as_float(sc[6]);
  float myloss = 0.f;
  unsigned mycnt = 0u;
  if (kl[idx] >= thr) {
    mycnt = 1u;
    const float g = gdist[idx];
    if (g != 0.f) {
      const int ww = idx % W_;
      const int hh = (idx / W_) % H_;
      const int dd = idx / HW_;
      const float p0 = inp[idx];
      const float p1 = inp[N_ + idx];
      // DIRECTIONS in torch-loop order: i outer, j mid, k inner, skipping (0,0,0)
      constexpr int DI[26] = {-1,-1,-1,-1,-1,-1,-1,-1,-1, 0,0,0,0,0,0,0,0, 1,1,1,1,1,1,1,1,1};
      constexpr int DJ[26] = {-1,-1,-1, 0,0,0, 1,1,1, -1,-1,-1, 0,0, 1,1,1, -1,-1,-1, 0,0,0, 1,1,1};
      constexpr int DK[26] = {-1,0,1, -1,0,1, -1,0,1, -1,0,1, -1,1, -1,0,1, -1,0,1, -1,0,1, -1,0,1};
      float klv[26], dst[26];
      float s = 0.f;
#pragma unroll
      for (int t = 0; t < 26; t++) {
        const int nd = dd + DI[t], nh = hh + DJ[t], nw = ww + DK[t];
        const bool inb = ((unsigned)nd < (unsigned)D_) && ((unsigned)nh < (unsigned)H_) &&
                         ((unsigned)nw < (unsigned)W_);
        const int nidx = (nd * H_ + nh) * W_ + nw;
        dst[t] = inb ? gdist[nidx] : 0.f;
        // coordinate masks from the reference's (batch,d,h) indexing bug, specialized to B=1:
        //  i==+1 -> 0; j==+1 -> 0; j==-1 -> only d==0; k==+1 -> only h==159; k==-1 -> only h==0
        bool keep;
        if (DI[t] == 1 || DJ[t] == 1) keep = false;
        else {
          keep = true;
          if (DJ[t] == -1) keep = (dd == 0);
          if (DK[t] == 1) keep = keep && (hh == H_ - 1);
          if (DK[t] == -1) keep = keep && (hh == 0);
        }
        float kt = 0.f;
        if (keep) {
          float t0 = 0.f, t1 = 0.f;
          if (inb) { t0 = inp[nidx]; t1 = inp[N_ + nidx]; }
          const float a0 = (t0 > 0.f) ? t0 * logf(t0) : 0.f;
          const float a1 = (t1 > 0.f) ? t1 * logf(t1) : 0.f;
          const float kldm = 0.5f * ((a0 - t0 * p0) + (a1 - t1 * p1));
          kt = expf(kldm);
        }
        klv[t] = kt;
        s += kt;
      }
      const float denom = (s == 0.f) ? 1.f : s;
      int amin = 0;
      float dmin = dst[0];
#pragma unroll
      for (int t = 1; t < 26; t++) {
        if (dst[t] < dmin) { dmin = dst[t]; amin = t; }  // first-min, like jnp.argmin
      }
      const float yoff = (float)(0.2 / 26.0);
      float bsum = 0.f;
#pragma unroll
      for (int t = 0; t < 26; t++) {
        const float x = klv[t] / denom;
        const float y = (t == amin) ? 0.8f : yoff;
        bsum += fmaxf(x, 0.f) - x * y + log1pf(expf(-fabsf(x)));
      }
      myloss = (fminf(g, 20.f) / 20.f) * (bsum / 26.f);
    }
  }
  __shared__ float ls[256];
  __shared__ unsigned lc[256];
  ls[tid] = myloss;
  lc[tid] = mycnt;
  __syncthreads();
  for (int o = 128; o > 0; o >>= 1) {
    if (tid < o) { ls[tid] += ls[tid + o]; lc[tid] += lc[tid + o]; }
    __syncthreads();
  }
  if (tid == 0) { psum[blockIdx.x] = ls[0]; pcnt[blockIdx.x] = lc[0]; }
}

// ---------------- deterministic final reduce ----------------
__global__ __launch_bounds__(256) void k_reduce(const float* __restrict__ psum,
                                                const unsigned* __restrict__ pcnt,
                                                float* __restrict__ out) {
  __shared__ float ls[256];
  __shared__ unsigned lc[256];
  const int t = threadIdx.x;
  float s = 0.f;
  unsigned c = 0;
  for (int i = t; i < NBLK; i += 256) { s += psum[i]; c += pcnt[i]; }
  ls[t] = s;
  lc[t] = c;
  __syncthreads();
  for (int o = 128; o > 0; o >>= 1) {
    if (t < o) { ls[t] += ls[t + o]; lc[t] += lc[t + o]; }
    __syncthreads();
  }
  if (t == 0) out[0] = ls[0] / (float)lc[0];
}

extern "C" void kernel_launch(void* const* d_in, const int* in_sizes, int n_in,
                              void* d_out, int out_size, void* d_ws, size_t ws_size,
                              hipStream_t stream) {
  (void)in_sizes; (void)n_in; (void)out_size; (void)ws_size;
  const float* inp = (const float*)d_in[0];
  const int* tgt = (const int*)d_in[1];
  float* out = (float*)d_out;
  char* ws = (char*)d_ws;

  float* kl = (float*)(ws + OFF_KL);
  float* fA = (float*)(ws + OFF_FA);
  float* fB = (float*)(ws + OFF_FB);
  unsigned* g1 = (unsigned*)(ws + OFF_G1);
  unsigned* g2 = (unsigned*)(ws + OFF_G2);
  unsigned* g3 = (unsigned*)(ws + OFF_G3);
  unsigned* sc = (unsigned*)(ws + OFF_SC);
  float* ps = (float*)(ws + OFF_PS);
  unsigned* pc = (unsigned*)(ws + OFF_PC);

  k_zero<<<(ZERO_WORDS + 255) / 256, 256, 0, stream>>>(g1);  // g1,g2,g3,sc contiguous

  k_prep<<<HBLK, 256, 0, stream>>>(inp, tgt, kl, fA, g1);

  // EDT: three early-exit axis passes (bit-exact vs brute force)
  k_dt<HW_, D_, 0, false><<<NBLK, 256, 0, stream>>>(fA, fB);
  k_dt<W_, H_, 1, false><<<NBLK, 256, 0, stream>>>(fB, fA);
  k_dt<1, W_, 2, true><<<NBLK, 256, 0, stream>>>(fA, fB);  // fB = gdb_dist

  // 12+12+8 radix select for the 0.99-quantile order statistic
  k_sel<<<1, 256, 0, stream>>>(g1, 4096, nullptr, K1_, sc + 0, sc + 1);
  k_hist2<<<HBLK, 256, 0, stream>>>(kl, sc, g2);
  k_sel<<<1, 256, 0, stream>>>(g2, 4096, sc + 1, 0u, sc + 2, sc + 3);
  k_hist3<<<HBLK, 256, 0, stream>>>(kl, sc, g3);
  k_sel<<<1, 256, 0, stream>>>(g3, 256, sc + 3, 0u, sc + 4, sc + 5);
  k_thr<<<1, 1, 0, stream>>>(sc);

  k_loss<<<NBLK, 256, 0, stream>>>(inp, kl, fB, sc, ps, pc);
  k_reduce<<<1, 256, 0, stream>>>(ps, pc, out);
}

// Round 13
// 78.821 us; speedup vs baseline: 1.2578x; 1.2578x over previous
//
#include <hip/hip_runtime.h>
#include <math.h>

// Problem dims (fixed by setup_inputs): inp [1,2,48,160,160] f32, target [1,48,160,160] i32
#define D_ 48
#define H_ 160
#define W_ 160
#define HW_ 25600
#define N_ 1228800
#define NBLK 4800          // N_/256, 1 voxel/thread (high-TLP)
#define HBLK 600           // k_prep: 8 consecutive elems/thread
#define NREG 16            // compaction regions (300 blocks each), counters on separate cache lines
#define RBLK (NBLK / NREG) // 300
#define REGCAP (N_ / NREG) // 76800 (capacity exact by construction)
#define K1_ 1216512u       // 1-based rank of sorted index floor(0.99*(N-1)); frac==0 in f32 (R1: absmax 0.0)

static_assert(N_ == D_ * HW_, "dims");
static_assert(N_ == NBLK * 256, "grid");
static_assert(N_ == HBLK * 256 * 8, "prep grid");
static_assert(W_ % 8 == 0, "chunks stay in-row");

// ---- workspace layout (bytes) ----
#define OFF_KL   0u
#define OFF_FA   (N_ * 4u)
#define OFF_FB   (2u * N_ * 4u)
#define OFF_CAND (3u * N_ * 4u)            // NREG dense regions x REGCAP u32
#define OFF_G1   (4u * N_ * 4u)            // 4096 u32
#define OFF_SC   (OFF_G1 + 4096u * 4u)     // 16 u32 scalars
#define OFF_CTR  (OFF_SC + 64u)            // 16 counters x 16 u32 stride (64B apart, distinct lines)
#define OFF_PS   (OFF_CTR + 1024u)
#define OFF_PC   (OFF_PS + NBLK * 4u)
// sc: [0]=b1 [1]=rank-in-bucket [6]=thr bits

__device__ __forceinline__ unsigned fkey(float v) {
  unsigned u = __float_as_uint(v);
  return (u & 0x80000000u) ? ~u : (u | 0x80000000u);  // monotone map: float asc -> uint asc
}

// ---------------- zero g1 + scalars + region counters ----------------
__global__ __launch_bounds__(256) void k_zero(unsigned* __restrict__ g1,
                                              unsigned* __restrict__ sc) {
  const int i = blockIdx.x * 256 + threadIdx.x;
  if (i < 4096) g1[i] = 0u;
  else if (i < 4368) sc[i - 4096] = 0u;   // sc[0..15] + ctr (sc+16..sc+271), contiguous
}

// ---------------- kl_vals + initial dist field + level-1 (hi-12) histogram ----------------
// Vectorized (G13): 8 consecutive voxels/thread; float4/int4 loads; W-neighbor via in-register
// shift (+1 scalar at chunk end); all lane extraction fully unrolled -> constant indices.
__global__ __launch_bounds__(256) void k_prep(const float* __restrict__ inp,
                                              const int* __restrict__ tgt,
                                              float* __restrict__ kl,
                                              float* __restrict__ f0,
                                              unsigned* __restrict__ ghist) {
  __shared__ unsigned h[4096];
  const int tid = threadIdx.x;
  for (int i = tid; i < 4096; i += 256) h[i] = 0;
  __syncthreads();

  const int base = blockIdx.x * 2048 + tid * 8;   // 600*256*8 = N_
  const int ww = base % W_;                        // chunk-uniform (row-aligned chunks)
  const int hh = (base / W_) % H_;
  const int dd = base / HW_;
  const bool hasW8 = (ww < W_ - 8);                // elem 7's w-neighbor lives in next chunk
  const bool hasH = (hh < H_ - 1);
  const bool hasD = (dd < D_ - 1);

  float c0[8], c1[8], h0[8], h1[8], d0[8], d1[8];
  int tc[8], th[8], td[8];
  *(float4*)&c0[0] = *(const float4*)&inp[base];
  *(float4*)&c0[4] = *(const float4*)&inp[base + 4];
  *(float4*)&c1[0] = *(const float4*)&inp[N_ + base];
  *(float4*)&c1[4] = *(const float4*)&inp[N_ + base + 4];
  const float w0n = hasW8 ? inp[base + 8] : 0.f;
  const float w1n = hasW8 ? inp[N_ + base + 8] : 0.f;
  if (hasH) {
    *(float4*)&h0[0] = *(const float4*)&inp[base + W_];
    *(float4*)&h0[4] = *(const float4*)&inp[base + W_ + 4];
    *(float4*)&h1[0] = *(const float4*)&inp[N_ + base + W_];
    *(float4*)&h1[4] = *(const float4*)&inp[N_ + base + W_ + 4];
  }
  if (hasD) {
    *(float4*)&d0[0] = *(const float4*)&inp[base + HW_];
    *(float4*)&d0[4] = *(const float4*)&inp[base + HW_ + 4];
    *(float4*)&d1[0] = *(const float4*)&inp[N_ + base + HW_];
    *(float4*)&d1[4] = *(const float4*)&inp[N_ + base + HW_ + 4];
  }
  *(int4*)&tc[0] = *(const int4*)&tgt[base];
  *(int4*)&tc[4] = *(const int4*)&tgt[base + 4];
  const int twn = hasW8 ? tgt[base + 8] : 0;
  if (hasH) {
    *(int4*)&th[0] = *(const int4*)&tgt[base + W_];
    *(int4*)&th[4] = *(const int4*)&tgt[base + W_ + 4];
  }
  if (hasD) {
    *(int4*)&td[0] = *(const int4*)&tgt[base + HW_];
    *(int4*)&td[4] = *(const int4*)&tgt[base + HW_ + 4];
  }

  float klo[8], fo[8];
#pragma unroll
  for (int e = 0; e < 8; e++) {
    const float p0 = c0[e], p1 = c1[e];
    float klh = -1.0f, klv = -1.0f, kld = -1.0f;
    if (ww + e < W_ - 1) {                       // e<7: in-chunk shift; e==7: next-chunk scalar
      const float t0 = (e < 7) ? c0[e + 1] : w0n;
      const float t1 = (e < 7) ? c1[e + 1] : w1n;
      const float a0 = (t0 > 0.f) ? t0 * logf(t0) : 0.f;
      const float a1 = (t1 > 0.f) ? t1 * logf(t1) : 0.f;
      klh = 0.5f * ((a0 - t0 * p0) + (a1 - t1 * p1));
    }
    if (hasH) {
      const float t0 = h0[e], t1 = h1[e];
      const float a0 = (t0 > 0.f) ? t0 * logf(t0) : 0.f;
      const float a1 = (t1 > 0.f) ? t1 * logf(t1) : 0.f;
      klv = 0.5f * ((a0 - t0 * p0) + (a1 - t1 * p1));
    }
    if (hasD) {
      const float t0 = d0[e], t1 = d1[e];
      const float a0 = (t0 > 0.f) ? t0 * logf(t0) : 0.f;
      const float a1 = (t1 > 0.f) ? t1 * logf(t1) : 0.f;
      kld = 0.5f * ((a0 - t0 * p0) + (a1 - t1 * p1));
    }
    const float kmax = fmaxf(fmaxf(klh, klv), kld);
    klo[e] = kmax;
    atomicAdd(&h[fkey(kmax) >> 20], 1u);

    const int tv = tc[e];
    const int t1v = (ww + e < W_ - 1) ? ((e < 7) ? tc[e + 1] : twn) : 0;
    const int t2v = hasH ? th[e] : 0;
    const int t3v = hasD ? td[e] : 0;
    fo[e] = (3 * tv != t1v + t2v + t3v) ? 0.f : 1e10f;
  }
  *(float4*)&kl[base] = *(float4*)&klo[0];
  *(float4*)&kl[base + 4] = *(float4*)&klo[4];
  *(float4*)&f0[base] = *(float4*)&fo[0];
  *(float4*)&f0[base + 4] = *(float4*)&fo[4];

  __syncthreads();
  for (int i = tid; i < 4096; i += 256) {
    const unsigned c = h[i];
    if (c) atomicAdd(&ghist[i], c);
  }
}

// ---------------- EDT axis D (1/thr) + level-1 rank-select in block 0 ----------------
// Early-exit scan is bit-exact vs brute force: f>=0 => RN(f[j]+r^2) >= r^2, so once r^2 >= m
// no candidate can lower the min; min over a set is order-independent.
__global__ __launch_bounds__(256) void k_dt_d(const float* __restrict__ fin,
                                              float* __restrict__ fout,
                                              const unsigned* __restrict__ g1,
                                              unsigned* __restrict__ sc) {
  const int idx = blockIdx.x * 256 + threadIdx.x;
  const int pos = idx / HW_;
  float m = fin[idx];
  for (int r = 1; r < D_; r++) {
    const float r2 = (float)(r * r);
    if (r2 >= m) break;
    const bool okm = (pos - r >= 0), okp = (pos + r < D_);
    if (!okm && !okp) break;
    if (okm) m = fminf(m, fin[idx - r * HW_] + r2);
    if (okp) m = fminf(m, fin[idx + r * HW_] + r2);
  }
  fout[idx] = m;

  if (blockIdx.x == 0) {
    __shared__ unsigned ssum[256];
    const int t = threadIdx.x;
    unsigned s = 0;
#pragma unroll
    for (int i = 0; i < 16; i++) s += g1[t * 16 + i];
    const unsigned mine = s;
    ssum[t] = s;
    __syncthreads();
    for (int o = 1; o < 256; o <<= 1) {
      const unsigned add = (t >= o) ? ssum[t - o] : 0u;
      __syncthreads();
      ssum[t] += add;
      __syncthreads();
    }
    const unsigned before = ssum[t] - mine;
    if (before < K1_ && K1_ <= before + mine) {
      unsigned cum = before;
      for (int i = 0; i < 16; i++) {
        const unsigned c = g1[t * 16 + i];
        if (cum < K1_ && K1_ <= cum + c) { sc[0] = (unsigned)(t * 16 + i); sc[1] = K1_ - cum; break; }
        cum += c;
      }
    }
  }
}

// ---------------- EDT axis H (1/thr) + 16-region dense compaction ----------------
// ballot/popc wave prefix + 4-entry LDS scan; ONE ticket atomic per block on ctr[reg*16],
// counters 64B apart => 16 independent lines, <=300 serialized RMWs each.
__global__ __launch_bounds__(256) void k_dt_h(const float* __restrict__ fin,
                                              float* __restrict__ fout,
                                              const float* __restrict__ kl,
                                              unsigned* __restrict__ cand,
                                              unsigned* __restrict__ ctr,
                                              const unsigned* __restrict__ sc) {
  const int tid = threadIdx.x;
  const int idx = blockIdx.x * 256 + tid;
  const int pos = (idx / W_) % H_;
  float m = fin[idx];
  for (int r = 1; r < H_; r++) {
    const float r2 = (float)(r * r);
    if (r2 >= m) break;
    const bool okm = (pos - r >= 0), okp = (pos + r < H_);
    if (!okm && !okp) break;
    if (okm) m = fminf(m, fin[idx - r * W_] + r2);
    if (okp) m = fminf(m, fin[idx + r * W_] + r2);
  }
  fout[idx] = m;

  const unsigned key = fkey(kl[idx]);
  const bool has = ((key >> 20) == sc[0]);
  const unsigned long long bal = __ballot(has);
  const int lane = tid & 63;
  const int wid = tid >> 6;
  const unsigned lpre = (unsigned)__popcll(bal & ((1ULL << lane) - 1ULL));
  __shared__ unsigned wcnt[4];
  __shared__ unsigned sbase;
  if (lane == 0) wcnt[wid] = (unsigned)__popcll(bal);
  __syncthreads();
  unsigned woff = 0;
  for (int w = 0; w < wid; w++) woff += wcnt[w];
  const unsigned btot = wcnt[0] + wcnt[1] + wcnt[2] + wcnt[3];
  const int reg = blockIdx.x / RBLK;
  if (tid == 0 && btot) sbase = atomicAdd(&ctr[reg * 16], btot);
  __syncthreads();
  if (has) cand[reg * REGCAP + sbase + woff + lpre] = key & 0xFFFFFu;
}

// ---------------- EDT axis W + sqrt (1/thr) + 12+8 radix select in block 0 ----------------
__global__ __launch_bounds__(256) void k_dt_w(const float* __restrict__ fin,
                                              float* __restrict__ fout,
                                              const unsigned* __restrict__ cand,
                                              const unsigned* __restrict__ ctr,
                                              unsigned* __restrict__ sc) {
  const int idx = blockIdx.x * 256 + threadIdx.x;
  const int pos = idx % W_;
  float m = fin[idx];
  for (int r = 1; r < W_; r++) {
    const float r2 = (float)(r * r);
    if (r2 >= m) break;
    const bool okm = (pos - r >= 0), okp = (pos + r < W_);
    if (!okm && !okp) break;
    if (okm) m = fminf(m, fin[idx - r] + r2);
    if (okp) m = fminf(m, fin[idx + r] + r2);
  }
  fout[idx] = sqrtf(m);

  if (blockIdx.x != 0) return;
  // ---- block 0 tail: rank-select over 16 dense candidate regions (coalesced runs) ----
  const int tid = threadIdx.x;
  const unsigned K = sc[1];
  __shared__ unsigned hist[4096];
  __shared__ unsigned ssum[256];
  __shared__ unsigned h2[256];
  __shared__ unsigned sBA, sKB;
  for (int i = tid; i < 4096; i += 256) hist[i] = 0;
  h2[tid] = 0;
  __syncthreads();
  for (int j = 0; j < NREG; j++) {
    const unsigned cj = ctr[j * 16];
    const unsigned rb = (unsigned)j * (unsigned)REGCAP;
    for (unsigned i = (unsigned)tid; i < cj; i += 256u)
      atomicAdd(&hist[(cand[rb + i] >> 8) & 0xFFFu], 1u);
  }
  __syncthreads();
  unsigned mine = 0;
#pragma unroll
  for (int i = 0; i < 16; i++) mine += hist[tid * 16 + i];
  ssum[tid] = mine;
  __syncthreads();
  for (int o = 1; o < 256; o <<= 1) {
    const unsigned add = (tid >= o) ? ssum[tid - o] : 0u;
    __syncthreads();
    ssum[tid] += add;
    __syncthreads();
  }
  {
    const unsigned before = ssum[tid] - mine;
    if (before < K && K <= before + mine) {
      unsigned cum = before;
      for (int i = 0; i < 16; i++) {
        const unsigned c = hist[tid * 16 + i];
        if (cum < K && K <= cum + c) { sBA = (unsigned)(tid * 16 + i); sKB = K - cum; break; }
        cum += c;
      }
    }
  }
  __syncthreads();
  const unsigned bA = sBA, KB = sKB;
  for (int j = 0; j < NREG; j++) {
    const unsigned cj = ctr[j * 16];
    const unsigned rb = (unsigned)j * (unsigned)REGCAP;
    for (unsigned i = (unsigned)tid; i < cj; i += 256u) {
      const unsigned v = cand[rb + i];
      if (((v >> 8) & 0xFFFu) == bA) atomicAdd(&h2[v & 0xFFu], 1u);
    }
  }
  __syncthreads();
  const unsigned mine2 = h2[tid];
  ssum[tid] = mine2;
  __syncthreads();
  for (int o = 1; o < 256; o <<= 1) {
    const unsigned add = (tid >= o) ? ssum[tid - o] : 0u;
    __syncthreads();
    ssum[tid] += add;
    __syncthreads();
  }
  {
    const unsigned before = ssum[tid] - mine2;
    if (before < KB && KB <= before + mine2) {
      const unsigned key = (sc[0] << 20) | (bA << 8) | (unsigned)tid;
      sc[6] = (key & 0x80000000u) ? (key & 0x7FFFFFFFu) : ~key;  // inverse of fkey
    }
  }
}

// ---------------- masked loss at each voxel + block partials (plain stores) ----------------
__global__ __launch_bounds__(256) void k_loss(const float* __restrict__ inp,
                                              const float* __restrict__ kl,
                                              const float* __restrict__ gdist,
                                              const unsigned* __restrict__ sc,
                                              float* __restrict__ psum,
                                              unsigned* __restrict__ pcnt) {
  const int tid = threadIdx.x;
  const int idx = blockIdx.x * 256 + tid;
  const float thr = __uint_as_float(sc[6]);
  float myloss = 0.f;
  unsigned mycnt = 0u;
  if (kl[idx] >= thr) {
    mycnt = 1u;
    const float g = gdist[idx];
    if (g != 0.f) {
      const int ww = idx % W_;
      const int hh = (idx / W_) % H_;
      const int dd = idx / HW_;
      const float p0 = inp[idx];
      const float p1 = inp[N_ + idx];
      // DIRECTIONS in torch-loop order: i outer, j mid, k inner, skipping (0,0,0)
      constexpr int DI[26] = {-1,-1,-1,-1,-1,-1,-1,-1,-1, 0,0,0,0,0,0,0,0, 1,1,1,1,1,1,1,1,1};
      constexpr int DJ[26] = {-1,-1,-1, 0,0,0, 1,1,1, -1,-1,-1, 0,0, 1,1,1, -1,-1,-1, 0,0,0, 1,1,1};
      constexpr int DK[26] = {-1,0,1, -1,0,1, -1,0,1, -1,0,1, -1,1, -1,0,1, -1,0,1, -1,0,1, -1,0,1};
      float klv[26], dst[26];
      float s = 0.f;
#pragma unroll
      for (int t = 0; t < 26; t++) {
        const int nd = dd + DI[t], nh = hh + DJ[t], nw = ww + DK[t];
        const bool inb = ((unsigned)nd < (unsigned)D_) && ((unsigned)nh < (unsigned)H_) &&
                         ((unsigned)nw < (unsigned)W_);
        const int nidx = (nd * H_ + nh) * W_ + nw;
        dst[t] = inb ? gdist[nidx] : 0.f;
        // coordinate masks from the reference's (batch,d,h) indexing bug, specialized to B=1:
        //  i==+1 -> 0; j==+1 -> 0; j==-1 -> only d==0; k==+1 -> only h==159; k==-1 -> only h==0
        bool keep;
        if (DI[t] == 1 || DJ[t] == 1) keep = false;
        else {
          keep = true;
          if (DJ[t] == -1) keep = (dd == 0);
          if (DK[t] == 1) keep = keep && (hh == H_ - 1);
          if (DK[t] == -1) keep = keep && (hh == 0);
        }
        float kt = 0.f;
        if (keep) {
          float t0 = 0.f, t1 = 0.f;
          if (inb) { t0 = inp[nidx]; t1 = inp[N_ + nidx]; }
          const float a0 = (t0 > 0.f) ? t0 * logf(t0) : 0.f;
          const float a1 = (t1 > 0.f) ? t1 * logf(t1) : 0.f;
          const float kldm = 0.5f * ((a0 - t0 * p0) + (a1 - t1 * p1));
          kt = expf(kldm);
        }
        klv[t] = kt;
        s += kt;
      }
      const float denom = (s == 0.f) ? 1.f : s;
      int amin = 0;
      float dmin = dst[0];
#pragma unroll
      for (int t = 1; t < 26; t++) {
        if (dst[t] < dmin) { dmin = dst[t]; amin = t; }  // first-min, like jnp.argmin
      }
      const float yoff = (float)(0.2 / 26.0);
      float bsum = 0.f;
#pragma unroll
      for (int t = 0; t < 26; t++) {
        const float x = klv[t] / denom;
        const float y = (t == amin) ? 0.8f : yoff;
        bsum += fmaxf(x, 0.f) - x * y + log1pf(expf(-fabsf(x)));
      }
      myloss = (fminf(g, 20.f) / 20.f) * (bsum / 26.f);
    }
  }
  __shared__ float ls[256];
  __shared__ unsigned lc[256];
  ls[tid] = myloss;
  lc[tid] = mycnt;
  __syncthreads();
  for (int o = 128; o > 0; o >>= 1) {
    if (tid < o) { ls[tid] += ls[tid + o]; lc[tid] += lc[tid + o]; }
    __syncthreads();
  }
  if (tid == 0) { psum[blockIdx.x] = ls[0]; pcnt[blockIdx.x] = lc[0]; }
}

// ---------------- deterministic final reduce (1 block, vectorized) ----------------
__global__ __launch_bounds__(256) void k_reduce(const float* __restrict__ psum,
                                                const unsigned* __restrict__ pcnt,
                                                float* __restrict__ out) {
  __shared__ float ls[256];
  __shared__ unsigned lc[256];
  const int t = threadIdx.x;
  float s = 0.f;
  unsigned c = 0;
  for (int g = t; g * 4 < NBLK; g += 256) {
    const float4 s4 = *reinterpret_cast<const float4*>(&psum[g * 4]);
    const uint4 c4 = *reinterpret_cast<const uint4*>(&pcnt[g * 4]);
    s += (s4.x + s4.y) + (s4.z + s4.w);
    c += c4.x + c4.y + c4.z + c4.w;
  }
  ls[t] = s;
  lc[t] = c;
  __syncthreads();
  for (int o = 128; o > 0; o >>= 1) {
    if (t < o) { ls[t] += ls[t + o]; lc[t] += lc[t + o]; }
    __syncthreads();
  }
  if (t == 0) out[0] = ls[0] / (float)lc[0];
}

extern "C" void kernel_launch(void* const* d_in, const int* in_sizes, int n_in,
                              void* d_out, int out_size, void* d_ws, size_t ws_size,
                              hipStream_t stream) {
  (void)in_sizes; (void)n_in; (void)out_size; (void)ws_size;
  const float* inp = (const float*)d_in[0];
  const int* tgt = (const int*)d_in[1];
  float* out = (float*)d_out;
  char* ws = (char*)d_ws;

  float* kl = (float*)(ws + OFF_KL);
  float* fA = (float*)(ws + OFF_FA);
  float* fB = (float*)(ws + OFF_FB);
  unsigned* cand = (unsigned*)(ws + OFF_CAND);
  unsigned* g1 = (unsigned*)(ws + OFF_G1);
  unsigned* sc = (unsigned*)(ws + OFF_SC);
  unsigned* ctr = (unsigned*)(ws + OFF_CTR);
  float* ps = (float*)(ws + OFF_PS);
  unsigned* pc = (unsigned*)(ws + OFF_PC);

  k_zero<<<18, 256, 0, stream>>>(g1, sc);                       // zeroes g1 + sc + ctr (contiguous)
  k_prep<<<HBLK, 256, 0, stream>>>(inp, tgt, kl, fA, g1);
  k_dt_d<<<NBLK, 256, 0, stream>>>(fA, fB, g1, sc);             // EDT D + sel1 (blk0)
  k_dt_h<<<NBLK, 256, 0, stream>>>(fB, fA, kl, cand, ctr, sc);  // EDT H + 16-region compaction
  k_dt_w<<<NBLK, 256, 0, stream>>>(fA, fB, cand, ctr, sc);      // EDT W + sqrt + sel23 (blk0)
  k_loss<<<NBLK, 256, 0, stream>>>(inp, kl, fB, sc, ps, pc);
  k_reduce<<<1, 256, 0, stream>>>(ps, pc, out);
}